// Round 20
// baseline (180.828 us; speedup 1.0000x reference)
//
#include <hip/hip_runtime.h>
#include <hip/hip_fp16.h>

// ---------------------------------------------------------------------------
// GCN layer: out[b][f][t][n] = relu( rsqrt(deg_in[n]) *
//     sum_{e: dst[e]=n} ( rsqrt(deg_out[src[e]]) * x[src[e]] @ W )[b][t][f] + bias[f] )
// Strategy: (1) degrees+CSR, (2) MFMA transform -> y[n][512] fp16 plain
//           node-major, (3) CSR gather-sum + epilogue + transpose-back.
// R20: transform multi-tile pipeline. Each block now covers 2 node-tiles
//      (4 passes) with one continuous cross-pass x-prefetch chain: W frags
//      loaded once per wave (was once per 2 passes -> 800K vmem instrs,
//      200MB L2 stream halved), and the exposed HBM latency at pipeline
//      fill drops from 1/2 of passes to 1/4. Resident blocks/CU unchanged
//      (3126 blocks still exceed the ~10-block/CU cap). Aggregate = R17
//      (fabric-pinned, frozen). Setup = R19.
// ---------------------------------------------------------------------------

typedef _Float16 half8 __attribute__((ext_vector_type(8)));
typedef float f32x4 __attribute__((ext_vector_type(4)));

extern "C" __global__ void k_deg(const int* __restrict__ src, const int* __restrict__ dst,
                                 int* __restrict__ deg_out, int* __restrict__ deg_in, int E) {
  int e = blockIdx.x * blockDim.x + threadIdx.x;
  if (e < E) {
    atomicAdd(&deg_out[src[e]], 1);
    atomicAdd(&deg_in[dst[e]], 1);
  }
}

// scan1 + rsqrt fused: block sums of deg_in, plus rs arrays.
extern "C" __global__ __launch_bounds__(256) void k_scan1(const int* __restrict__ deg_in,
                                                          const int* __restrict__ deg_out,
                                                          int* __restrict__ bsum,
                                                          float* __restrict__ rs_out,
                                                          float* __restrict__ rs_in, int N) {
  __shared__ int red[256];
  int tid = threadIdx.x;
  int i = blockIdx.x * 256 + tid;
  int di = (i < N) ? deg_in[i] : 0;
  red[tid] = di;
  if (i < N) {
    int a = deg_out[i] > 1 ? deg_out[i] : 1;
    int b = di > 1 ? di : 1;
    rs_out[i] = rsqrtf((float)a);
    rs_in[i]  = rsqrtf((float)b);
  }
  __syncthreads();
  #pragma unroll
  for (int off = 128; off > 0; off >>= 1) {
    if (tid < off) red[tid] += red[tid + off];
    __syncthreads();
  }
  if (tid == 0) bsum[blockIdx.x] = red[0];
}

// scan3 (scan2 folded in): per-node exclusive scan within block + local scan
// of bsum for the block offset. Writes offs[i] AND cursor[i]=offs[i].
extern "C" __global__ __launch_bounds__(256) void k_scan3(const int* __restrict__ deg,
                                                          const int* __restrict__ bsum,
                                                          int* __restrict__ offs,
                                                          int* __restrict__ cursor,
                                                          int M, int N) {
  __shared__ int sc[256];
  __shared__ int bs[256];
  int tid = threadIdx.x;

  int bv = (tid < M) ? bsum[tid] : 0;
  bs[tid] = bv;
  __syncthreads();
  #pragma unroll
  for (int off = 1; off < 256; off <<= 1) {
    int t = bs[tid];
    if (tid >= off) t += bs[tid - off];
    __syncthreads();
    bs[tid] = t;
    __syncthreads();
  }
  int boff = (blockIdx.x > 0) ? bs[blockIdx.x - 1] : 0;
  if (blockIdx.x == 0 && tid == 0) offs[N] = bs[255];  // total edges

  int i = blockIdx.x * 256 + tid;
  int v = (i < N) ? deg[i] : 0;
  sc[tid] = v;
  __syncthreads();
  #pragma unroll
  for (int off = 1; off < 256; off <<= 1) {
    int t = sc[tid];
    if (tid >= off) t += sc[tid - off];
    __syncthreads();
    sc[tid] = t;
    __syncthreads();
  }
  if (i < N) {
    int o = boff + sc[tid] - v;
    offs[i] = o;
    cursor[i] = o;   // preload for scatter's single-atomic path
  }
}

extern "C" __global__ void k_scatter(const int* __restrict__ src, const int* __restrict__ dst,
                                     int* __restrict__ cursor,
                                     int* __restrict__ csr_src, int E) {
  int e = blockIdx.x * blockDim.x + threadIdx.x;
  if (e < E) {
    int pos = atomicAdd(&cursor[dst[e]], 1);
    csr_src[pos] = src[e];
  }
}

// MFMA transform (R20). Block = 128 thr = 2 waves; grid (ceil(tiles/2), 2).
// Block covers 2 node-tiles x bt quad blockIdx.y*4..+3 (wave w -> bt
// w*2+{0,1}). 4 passes: pass = tile*2 + p; continuous cross-pass x prefetch;
// W frags loaded once per wave. Per tile: MFMA -> LDS stage -> uint4 stores.
extern "C" __global__ __launch_bounds__(128) void k_transform(
    const float* __restrict__ in_feat, const float* __restrict__ W,
    const float* __restrict__ rs_out, __half* __restrict__ y, int N) {
  __shared__ __half ytile[16][264];   // 256 ch + 8 pad (row stride 528B)
  int tid = threadIdx.x;
  int wave = tid >> 6, l = tid & 63;
  int col = l & 15;      // A row (node) on load side; D col (f) on store side
  int kg  = l >> 4;      // k-group 0..3
  int tile0 = blockIdx.x * 2;
  int btbase = blockIdx.y * 4 + wave * 2;   // bt = btbase, btbase+1

  half8 wf[4][2];
  #pragma unroll
  for (int ft = 0; ft < 4; ++ft)
    #pragma unroll
    for (int ks = 0; ks < 2; ++ks)
      #pragma unroll
      for (int j = 0; j < 8; ++j)
        wf[ft][ks][j] = (_Float16)W[(ks * 32 + kg * 8 + j) * 64 + ft * 16 + col];

  size_t hs = (size_t)4 * (size_t)N;

  float c0[8], c1[8], rs_cur;
  {  // pipeline fill: pass 0 = (tile0, bt=btbase)
    int nA = tile0 * 16 + col;
    bool ok = (nA < N);
    rs_cur = ok ? rs_out[nA] : 0.0f;
    int b = btbase >> 2, t = btbase & 3;
    const float* xp = in_feat + (size_t)(b * 256 + t) * (size_t)N + nA;
    #pragma unroll
    for (int j = 0; j < 8; ++j) c0[j] = ok ? xp[(size_t)(kg * 8 + j) * hs] : 0.0f;
    #pragma unroll
    for (int j = 0; j < 8; ++j) c1[j] = ok ? xp[(size_t)(32 + kg * 8 + j) * hs] : 0.0f;
  }

  #pragma unroll
  for (int pass = 0; pass < 4; ++pass) {
    int tile = tile0 + (pass >> 1);
    int p = pass & 1;
    int n0 = tile * 16;

    // prefetch next pass's x (and rs at tile boundaries)
    float nx0[8], nx1[8], rs_nxt = rs_cur;
    if (pass < 3) {
      int pn = pass + 1;
      int tn = tile0 + (pn >> 1);
      int nAn = tn * 16 + col;
      bool okn = (nAn < N);
      if ((pn & 1) == 0) rs_nxt = okn ? rs_out[nAn] : 0.0f;  // new tile
      int btn = btbase + (pn & 1);
      int bn = btn >> 2, tt = btn & 3;
      const float* xpn = in_feat + (size_t)(bn * 256 + tt) * (size_t)N + nAn;
      #pragma unroll
      for (int j = 0; j < 8; ++j) nx0[j] = okn ? xpn[(size_t)(kg * 8 + j) * hs] : 0.0f;
      #pragma unroll
      for (int j = 0; j < 8; ++j) nx1[j] = okn ? xpn[(size_t)(32 + kg * 8 + j) * hs] : 0.0f;
    }

    // compute current pass
    half8 a0, a1;
    #pragma unroll
    for (int j = 0; j < 8; ++j) {
      a0[j] = (_Float16)(c0[j] * rs_cur);
      a1[j] = (_Float16)(c1[j] * rs_cur);
    }
    int btloc = wave * 2 + p;   // 0..3 within the block's bt quad
    #pragma unroll
    for (int ft = 0; ft < 4; ++ft) {
      f32x4 acc = {0.f, 0.f, 0.f, 0.f};
      acc = __builtin_amdgcn_mfma_f32_16x16x32_f16(a0, wf[ft][0], acc, 0, 0, 0);
      acc = __builtin_amdgcn_mfma_f32_16x16x32_f16(a1, wf[ft][1], acc, 0, 0, 0);
      #pragma unroll
      for (int r = 0; r < 4; ++r)
        ytile[kg * 4 + r][btloc * 64 + ft * 16 + col] = __float2half(acc[r]);
    }

    // tile complete after p==1: vectorized store, then LDS reuse barrier
    if (p == 1) {
      __syncthreads();
      int row = tid >> 3, seg = tid & 7;
      int nr = n0 + row;
      if (nr < N) {
        const uint4* lp = (const uint4*)&ytile[row][0];   // 32 uint4 per row
        uint4* gp = (uint4*)(y + (size_t)nr * 512 + blockIdx.y * 256);
        #pragma unroll
        for (int q = 0; q < 4; ++q) gp[seg + q * 8] = lp[seg + q * 8];
      }
      __syncthreads();
    }

    // rotate pipeline
    if (pass < 3) {
      #pragma unroll
      for (int j = 0; j < 8; ++j) { c0[j] = nx0[j]; c1[j] = nx1[j]; }
      rs_cur = rs_nxt;
    }
  }
}

// Aggregate (R9 body + R17 NT out stores — 72.3us, fabric-pinned, frozen).
extern "C" __global__ __launch_bounds__(512) void k_aggregate(
    const __half* __restrict__ y, const int* __restrict__ offs,
    const int* __restrict__ csr_src, const float* __restrict__ rs_in,
    const float* __restrict__ bvec, float* __restrict__ out, int N) {
  __shared__ float agg[16 * 513];
  int tid = threadIdx.x;
  int lane = tid & 63, wave = tid >> 6;   // 8 waves
  int n0 = blockIdx.x * 16;

#define ACC_EDGE(s)                                                          \
  {                                                                          \
    const uint2* rp = (const uint2*)(y + (size_t)(s) * 512);                 \
    uint2 ua = rp[lane];                                                     \
    uint2 ub = rp[64 + lane];                                                \
    float2 f;                                                                \
    f = __half22float2(*(const __half2*)&ua.x); accA.x += f.x; accA.y += f.y;\
    f = __half22float2(*(const __half2*)&ua.y); accA.z += f.x; accA.w += f.y;\
    f = __half22float2(*(const __half2*)&ub.x); accB.x += f.x; accB.y += f.y;\
    f = __half22float2(*(const __half2*)&ub.y); accB.z += f.x; accB.w += f.y;\
  }

  #pragma unroll
  for (int k = 0; k < 2; ++k) {
    int nl = k * 8 + wave;
    int n = n0 + nl;
    float4 accA = {0.f, 0.f, 0.f, 0.f};
    float4 accB = {0.f, 0.f, 0.f, 0.f};
    if (n < N) {
      int j0 = offs[n], j1 = offs[n + 1];
      for (int base = j0; base < j1; base += 64) {
        int idxv = csr_src[base + lane];  // coalesced block of up to 64 indices
        int m = j1 - base; if (m > 64) m = 64;
        int e = 0;
        for (; e + 3 < m; e += 4) {
          int s0 = __builtin_amdgcn_readlane(idxv, e);
          int s1 = __builtin_amdgcn_readlane(idxv, e + 1);
          int s2 = __builtin_amdgcn_readlane(idxv, e + 2);
          int s3 = __builtin_amdgcn_readlane(idxv, e + 3);
          ACC_EDGE(s0); ACC_EDGE(s1); ACC_EDGE(s2); ACC_EDGE(s3);
        }
        for (; e < m; ++e) {
          int s0 = __builtin_amdgcn_readlane(idxv, e);
          ACC_EDGE(s0);
        }
      }
    }
    *(float4*)&agg[nl * 513 + lane * 4] = accA;
    *(float4*)&agg[nl * 513 + 256 + lane * 4] = accB;
  }
#undef ACC_EDGE
  __syncthreads();

  // epilogue: scale, bias, relu, transpose-back; NT stores (R17).
  int nl = tid & 15;
  int r0 = tid >> 4;  // 0..31
  int n = n0 + nl;
  float rs = (n < N) ? rs_in[n] : 0.0f;
  #pragma unroll 4
  for (int it = 0; it < 16; ++it) {
    int c = it * 32 + r0;          // c = (b*4+t)*64 + f
    float v = agg[nl * 513 + c];
    int f = c & 63, bt = c >> 6;
    int b = bt >> 2, t = bt & 3;
    v = v * rs + bvec[f];
    v = fmaxf(v, 0.0f);
    if (n < N)
      __builtin_nontemporal_store(v, &out[(size_t)((b * 64 + f) * 4 + t) * (size_t)N + n]);
  }
}

extern "C" void kernel_launch(void* const* d_in, const int* in_sizes, int n_in,
                              void* d_out, int out_size, void* d_ws, size_t ws_size,
                              hipStream_t stream) {
  const float* in_feat = (const float*)d_in[0];
  const int*   src     = (const int*)d_in[1];
  const int*   dst     = (const int*)d_in[2];
  const float* W       = (const float*)d_in[3];
  const float* bvec    = (const float*)d_in[4];
  float* out = (float*)d_out;

  int N = in_sizes[0] / 512;   // B*H*T = 2*64*4 = 512
  int E = in_sizes[1];

  int A  = (N + 64) & ~63;     // room for N+1 offsets, 64-aligned
  int EA = (E + 63) & ~63;
  int M  = (N + 255) / 256;    // scan blocks (<= 256 for N <= 65536)
  int T  = (N + 15) / 16;      // node tiles
  int GX = (T + 1) / 2;        // transform blocks per bt-half (2 tiles each)

  // layout: the two arrays needing zero-init come first (one memset)
  int*   deg_out_i = (int*)d_ws;        // [A]  zeroed
  int*   deg_in_i  = deg_out_i + A;     // [A]  zeroed
  int*   cursor    = deg_in_i + A;      // [A]  written by scan3
  int*   offs      = cursor + A;        // [A]  (N+1 used, written by scan3)
  int*   bsum      = offs + A;          // [256]
  float* rs_out    = (float*)(bsum + 256);
  float* rs_in     = rs_out + A;
  int*   csr_src   = (int*)(rs_in + A); // [EA] (+slack: y follows, overreads safe)
  __half* y        = (__half*)(csr_src + EA); // [N*512] fp16, plain layout

  hipMemsetAsync(deg_out_i, 0, (size_t)(2 * A) * sizeof(int), stream);
  hipLaunchKernelGGL(k_deg, dim3((E + 255) / 256), dim3(256), 0, stream,
                     src, dst, deg_out_i, deg_in_i, E);
  hipLaunchKernelGGL(k_scan1, dim3(M), dim3(256), 0, stream,
                     deg_in_i, deg_out_i, bsum, rs_out, rs_in, N);
  hipLaunchKernelGGL(k_scan3, dim3(M), dim3(256), 0, stream,
                     deg_in_i, bsum, offs, cursor, M, N);
  hipLaunchKernelGGL(k_scatter, dim3((E + 255) / 256), dim3(256), 0, stream,
                     src, dst, cursor, csr_src, E);
  hipLaunchKernelGGL(k_transform, dim3(GX, 2), dim3(128), 0, stream,
                     in_feat, W, rs_out, y, N);
  hipLaunchKernelGGL(k_aggregate, dim3((N + 15) / 16), dim3(512), 0, stream,
                     y, offs, csr_src, rs_in, bvec, out, N);
}

// Round 22
// 173.725 us; speedup vs baseline: 1.0409x; 1.0409x over previous
//
#include <hip/hip_runtime.h>
#include <hip/hip_fp16.h>

// ---------------------------------------------------------------------------
// GCN layer: out[b][f][t][n] = relu( rsqrt(deg_in[n]) *
//     sum_{e: dst[e]=n} ( rsqrt(deg_out[src[e]]) * x[src[e]] @ W )[b][t][f] + bias[f] )
// Strategy: (1) degrees+CSR, (2) MFMA transform -> y[n][512] fp16 plain
//           node-major, (3) CSR gather-sum + epilogue + transpose-back.
// R22: R21 store-bug fix. Per pass each node row-slice is 64 halfs = 8 uint4;
//      4 threads/node must store TWO uint4 each (sg and sg+4) — R21 stored
//      one, leaving channels 32..63 poisoned (absmax 2.2). Rest identical:
//      LDS-staged x (float4 1KB/instr loads, rs-scale+fp16 at stage),
//      xs[64][68], W frags VGPR-resident, 32 waves/CU cap.
// ---------------------------------------------------------------------------

typedef _Float16 half8 __attribute__((ext_vector_type(8)));
typedef float f32x4 __attribute__((ext_vector_type(4)));

extern "C" __global__ void k_deg(const int* __restrict__ src, const int* __restrict__ dst,
                                 int* __restrict__ deg_out, int* __restrict__ deg_in, int E) {
  int e = blockIdx.x * blockDim.x + threadIdx.x;
  if (e < E) {
    atomicAdd(&deg_out[src[e]], 1);
    atomicAdd(&deg_in[dst[e]], 1);
  }
}

// scan1 + rsqrt fused: block sums of deg_in, plus rs arrays.
extern "C" __global__ __launch_bounds__(256) void k_scan1(const int* __restrict__ deg_in,
                                                          const int* __restrict__ deg_out,
                                                          int* __restrict__ bsum,
                                                          float* __restrict__ rs_out,
                                                          float* __restrict__ rs_in, int N) {
  __shared__ int red[256];
  int tid = threadIdx.x;
  int i = blockIdx.x * 256 + tid;
  int di = (i < N) ? deg_in[i] : 0;
  red[tid] = di;
  if (i < N) {
    int a = deg_out[i] > 1 ? deg_out[i] : 1;
    int b = di > 1 ? di : 1;
    rs_out[i] = rsqrtf((float)a);
    rs_in[i]  = rsqrtf((float)b);
  }
  __syncthreads();
  #pragma unroll
  for (int off = 128; off > 0; off >>= 1) {
    if (tid < off) red[tid] += red[tid + off];
    __syncthreads();
  }
  if (tid == 0) bsum[blockIdx.x] = red[0];
}

// scan3 (scan2 folded in): per-node exclusive scan within block + local scan
// of bsum for the block offset. Writes offs[i] AND cursor[i]=offs[i].
extern "C" __global__ __launch_bounds__(256) void k_scan3(const int* __restrict__ deg,
                                                          const int* __restrict__ bsum,
                                                          int* __restrict__ offs,
                                                          int* __restrict__ cursor,
                                                          int M, int N) {
  __shared__ int sc[256];
  __shared__ int bs[256];
  int tid = threadIdx.x;

  int bv = (tid < M) ? bsum[tid] : 0;
  bs[tid] = bv;
  __syncthreads();
  #pragma unroll
  for (int off = 1; off < 256; off <<= 1) {
    int t = bs[tid];
    if (tid >= off) t += bs[tid - off];
    __syncthreads();
    bs[tid] = t;
    __syncthreads();
  }
  int boff = (blockIdx.x > 0) ? bs[blockIdx.x - 1] : 0;
  if (blockIdx.x == 0 && tid == 0) offs[N] = bs[255];  // total edges

  int i = blockIdx.x * 256 + tid;
  int v = (i < N) ? deg[i] : 0;
  sc[tid] = v;
  __syncthreads();
  #pragma unroll
  for (int off = 1; off < 256; off <<= 1) {
    int t = sc[tid];
    if (tid >= off) t += sc[tid - off];
    __syncthreads();
    sc[tid] = t;
    __syncthreads();
  }
  if (i < N) {
    int o = boff + sc[tid] - v;
    offs[i] = o;
    cursor[i] = o;   // preload for scatter's single-atomic path
  }
}

extern "C" __global__ void k_scatter(const int* __restrict__ src, const int* __restrict__ dst,
                                     int* __restrict__ cursor,
                                     int* __restrict__ csr_src, int E) {
  int e = blockIdx.x * blockDim.x + threadIdx.x;
  if (e < E) {
    int pos = atomicAdd(&cursor[dst[e]], 1);
    csr_src[pos] = src[e];
  }
}

// MFMA transform (R22 = R21 + store fix). Block = 256 thr = 4 waves; grid
// (ceil(N/64), 4). Block covers nodes n0..n0+63 for bt = blockIdx.y*2+{0,1}.
// Per bt: stage x (float4, rs-scaled, fp16) -> xs[64][68]; wave w computes
// nodes n0+16w..+15 (A-frags from xs, 8 MFMAs, D -> yt); block-wide uint4
// y store (2 uint4/thread = full 64-half rows). W frags VGPR-resident.
extern "C" __global__ __launch_bounds__(256) void k_transform(
    const float* __restrict__ in_feat, const float* __restrict__ W,
    const float* __restrict__ rs_out, __half* __restrict__ y, int N) {
  __shared__ __half xs[64][68];   // x tile: [h][n], stride 68 (frag reads 2-way-free)
  __shared__ __half yt[64][72];   // y tile: [node][ch], 144B rows (16B aligned)
  int tid = threadIdx.x;
  int wave = tid >> 6, l = tid & 63;
  int col = l & 15;      // node-within-subtile on A side; f-within-tile on D side
  int kg  = l >> 4;      // k-group 0..3
  int n0 = blockIdx.x * 64;

  // W fragments (VGPR-resident): wf[ft][ks][j] = W[(ks*32+kg*8+j)*64 + ft*16 + col]
  half8 wf[4][2];
  #pragma unroll
  for (int ft = 0; ft < 4; ++ft)
    #pragma unroll
    for (int ks = 0; ks < 2; ++ks)
      #pragma unroll
      for (int j = 0; j < 8; ++j)
        wf[ft][ks][j] = (_Float16)W[(ks * 32 + kg * 8 + j) * 64 + ft * 16 + col];

  // staging thread mapping: hq = tid>>4 (16 h-slots), nq = tid&15 (4-node cols)
  int hq = tid >> 4, nq = tid & 15;
  int nb = n0 + 4 * nq;
  float rs4[4];
  #pragma unroll
  for (int c = 0; c < 4; ++c)
    rs4[c] = (nb + c < N) ? rs_out[nb + c] : 0.0f;
  bool full4 = (nb + 3 < N);

  #pragma unroll
  for (int p = 0; p < 2; ++p) {
    int bt = blockIdx.y * 2 + p;
    int b = bt >> 2, t = bt & 3;
    const float* xbase = in_feat + (size_t)(b * 256 + t) * (size_t)N;

    __syncthreads();   // xs/yt safe to overwrite (prev pass readers done)
    // stage: 4 float4 rows per thread (h = hq + 16i), 1KB/instr per wave
    #pragma unroll
    for (int i = 0; i < 4; ++i) {
      int h = hq + 16 * i;
      const float* xp = xbase + (size_t)h * 4 * (size_t)N + nb;
      float v0 = 0.f, v1 = 0.f, v2 = 0.f, v3 = 0.f;
      if (full4) {
        float4 v = *(const float4*)xp;
        v0 = v.x; v1 = v.y; v2 = v.z; v3 = v.w;
      } else {
        if (nb < N)     v0 = xp[0];
        if (nb + 1 < N) v1 = xp[1];
        if (nb + 2 < N) v2 = xp[2];
      }
      __half2 h0 = __float22half2_rn(make_float2(v0 * rs4[0], v1 * rs4[1]));
      __half2 h1 = __float22half2_rn(make_float2(v2 * rs4[2], v3 * rs4[3]));
      uint2 u;
      u.x = *(unsigned int*)&h0;
      u.y = *(unsigned int*)&h1;
      *(uint2*)&xs[h][4 * nq] = u;
    }
    __syncthreads();

    // A-fragments from LDS: wave w owns nodes n0+16w+col
    int nloc = 16 * wave + col;
    half8 a0, a1;
    #pragma unroll
    for (int j = 0; j < 8; ++j) a0[j] = (_Float16)xs[kg * 8 + j][nloc];
    #pragma unroll
    for (int j = 0; j < 8; ++j) a1[j] = (_Float16)xs[32 + kg * 8 + j][nloc];

    #pragma unroll
    for (int ft = 0; ft < 4; ++ft) {
      f32x4 acc = {0.f, 0.f, 0.f, 0.f};
      acc = __builtin_amdgcn_mfma_f32_16x16x32_f16(a0, wf[ft][0], acc, 0, 0, 0);
      acc = __builtin_amdgcn_mfma_f32_16x16x32_f16(a1, wf[ft][1], acc, 0, 0, 0);
      #pragma unroll
      for (int r = 0; r < 4; ++r)
        yt[16 * wave + kg * 4 + r][ft * 16 + col] = __float2half(acc[r]);
    }
    __syncthreads();

    // y store: node = tid>>2 (64 nodes), sg = tid&3; TWO uint4 per thread
    // (sg and sg+4) = full 64-half (128B) row slice.
    int node = tid >> 2, sg = tid & 3;
    int nr = n0 + node;
    if (nr < N) {
      uint4* gp = (uint4*)(y + (size_t)nr * 512 + bt * 64);
      gp[sg]     = *(const uint4*)&yt[node][sg * 8];
      gp[sg + 4] = *(const uint4*)&yt[node][(sg + 4) * 8];
    }
  }
}

// Aggregate (R9 body + R17 NT out stores — 72.3us, fabric-pinned, frozen).
extern "C" __global__ __launch_bounds__(512) void k_aggregate(
    const __half* __restrict__ y, const int* __restrict__ offs,
    const int* __restrict__ csr_src, const float* __restrict__ rs_in,
    const float* __restrict__ bvec, float* __restrict__ out, int N) {
  __shared__ float agg[16 * 513];
  int tid = threadIdx.x;
  int lane = tid & 63, wave = tid >> 6;   // 8 waves
  int n0 = blockIdx.x * 16;

#define ACC_EDGE(s)                                                          \
  {                                                                          \
    const uint2* rp = (const uint2*)(y + (size_t)(s) * 512);                 \
    uint2 ua = rp[lane];                                                     \
    uint2 ub = rp[64 + lane];                                                \
    float2 f;                                                                \
    f = __half22float2(*(const __half2*)&ua.x); accA.x += f.x; accA.y += f.y;\
    f = __half22float2(*(const __half2*)&ua.y); accA.z += f.x; accA.w += f.y;\
    f = __half22float2(*(const __half2*)&ub.x); accB.x += f.x; accB.y += f.y;\
    f = __half22float2(*(const __half2*)&ub.y); accB.z += f.x; accB.w += f.y;\
  }

  #pragma unroll
  for (int k = 0; k < 2; ++k) {
    int nl = k * 8 + wave;
    int n = n0 + nl;
    float4 accA = {0.f, 0.f, 0.f, 0.f};
    float4 accB = {0.f, 0.f, 0.f, 0.f};
    if (n < N) {
      int j0 = offs[n], j1 = offs[n + 1];
      for (int base = j0; base < j1; base += 64) {
        int idxv = csr_src[base + lane];  // coalesced block of up to 64 indices
        int m = j1 - base; if (m > 64) m = 64;
        int e = 0;
        for (; e + 3 < m; e += 4) {
          int s0 = __builtin_amdgcn_readlane(idxv, e);
          int s1 = __builtin_amdgcn_readlane(idxv, e + 1);
          int s2 = __builtin_amdgcn_readlane(idxv, e + 2);
          int s3 = __builtin_amdgcn_readlane(idxv, e + 3);
          ACC_EDGE(s0); ACC_EDGE(s1); ACC_EDGE(s2); ACC_EDGE(s3);
        }
        for (; e < m; ++e) {
          int s0 = __builtin_amdgcn_readlane(idxv, e);
          ACC_EDGE(s0);
        }
      }
    }
    *(float4*)&agg[nl * 513 + lane * 4] = accA;
    *(float4*)&agg[nl * 513 + 256 + lane * 4] = accB;
  }
#undef ACC_EDGE
  __syncthreads();

  // epilogue: scale, bias, relu, transpose-back; NT stores (R17).
  int nl = tid & 15;
  int r0 = tid >> 4;  // 0..31
  int n = n0 + nl;
  float rs = (n < N) ? rs_in[n] : 0.0f;
  #pragma unroll 4
  for (int it = 0; it < 16; ++it) {
    int c = it * 32 + r0;          // c = (b*4+t)*64 + f
    float v = agg[nl * 513 + c];
    int f = c & 63, bt = c >> 6;
    int b = bt >> 2, t = bt & 3;
    v = v * rs + bvec[f];
    v = fmaxf(v, 0.0f);
    if (n < N)
      __builtin_nontemporal_store(v, &out[(size_t)((b * 64 + f) * 4 + t) * (size_t)N + n]);
  }
}

extern "C" void kernel_launch(void* const* d_in, const int* in_sizes, int n_in,
                              void* d_out, int out_size, void* d_ws, size_t ws_size,
                              hipStream_t stream) {
  const float* in_feat = (const float*)d_in[0];
  const int*   src     = (const int*)d_in[1];
  const int*   dst     = (const int*)d_in[2];
  const float* W       = (const float*)d_in[3];
  const float* bvec    = (const float*)d_in[4];
  float* out = (float*)d_out;

  int N = in_sizes[0] / 512;   // B*H*T = 2*64*4 = 512
  int E = in_sizes[1];

  int A  = (N + 64) & ~63;     // room for N+1 offsets, 64-aligned
  int EA = (E + 63) & ~63;
  int M  = (N + 255) / 256;    // scan blocks (<= 256 for N <= 65536)
  int GX = (N + 63) / 64;      // transform blocks (64-node tiles)

  // layout: the two arrays needing zero-init come first (one memset)
  int*   deg_out_i = (int*)d_ws;        // [A]  zeroed
  int*   deg_in_i  = deg_out_i + A;     // [A]  zeroed
  int*   cursor    = deg_in_i + A;      // [A]  written by scan3
  int*   offs      = cursor + A;        // [A]  (N+1 used, written by scan3)
  int*   bsum      = offs + A;          // [256]
  float* rs_out    = (float*)(bsum + 256);
  float* rs_in     = rs_out + A;
  int*   csr_src   = (int*)(rs_in + A); // [EA] (+slack: y follows, overreads safe)
  __half* y        = (__half*)(csr_src + EA); // [N*512] fp16, plain layout

  hipMemsetAsync(deg_out_i, 0, (size_t)(2 * A) * sizeof(int), stream);
  hipLaunchKernelGGL(k_deg, dim3((E + 255) / 256), dim3(256), 0, stream,
                     src, dst, deg_out_i, deg_in_i, E);
  hipLaunchKernelGGL(k_scan1, dim3(M), dim3(256), 0, stream,
                     deg_in_i, deg_out_i, bsum, rs_out, rs_in, N);
  hipLaunchKernelGGL(k_scan3, dim3(M), dim3(256), 0, stream,
                     deg_in_i, bsum, offs, cursor, M, N);
  hipLaunchKernelGGL(k_scatter, dim3((E + 255) / 256), dim3(256), 0, stream,
                     src, dst, cursor, csr_src, E);
  hipLaunchKernelGGL(k_transform, dim3(GX, 4), dim3(256), 0, stream,
                     in_feat, W, rs_out, y, N);
  hipLaunchKernelGGL(k_aggregate, dim3((N + 15) / 16), dim3(512), 0, stream,
                     y, offs, csr_src, rs_in, bvec, out, N);
}